// Round 1
// 615.227 us; speedup vs baseline: 1.0663x; 1.0663x over previous
//
#include <hip/hip_runtime.h>

// ---------------------------------------------------------------------------
// Model: xp = x @ W_ih^T + (b_ih + b_hh)   [bf16 MFMA GEMM, fp32 accumulate]
//        h_t = tanh(xp_t + h_{t-1} @ W_hh^T)   [fp32, latency-optimized scan]
//        out = LN(relu(relu(hT W1^T + b1) W2^T + b2))  [fused into RNN tail]
// ---------------------------------------------------------------------------

typedef __bf16 bf16x8 __attribute__((ext_vector_type(8)));
typedef float  f32x4  __attribute__((ext_vector_type(4)));

#define T_STEPS 512
#define I_DIM   2048
#define H_DIM   128
#define B_DIM   64
#define M_TOT   (B_DIM * T_STEPS)   // 32768

// RNE fp32 -> bf16 (inputs are finite; no NaN path needed)
__device__ __forceinline__ unsigned short f2bf(float f) {
    unsigned int u = __float_as_uint(f);
    u += 0x7FFFu + ((u >> 16) & 1u);
    return (unsigned short)(u >> 16);
}

// ---------------------------------------------------------------------------
// Kernel 1: xp[M,128] = x[M,2048] (bf16) @ W_ih[128,2048]^T (bf16) + bias
// BM=128, BN=128(=H), BK=64. 256 threads = 4 waves in 2x2, each wave 64x64.
// fp32 -> bf16 conversion fused into LDS staging (x read exactly once).
// ---------------------------------------------------------------------------
#define BM  128
#define BK  64
#define LDK 72   // LDS row stride in bf16 elems (+8 pad -> 2-way-max bank alias)

__global__ __launch_bounds__(256) void gemm_xp(
    const float* __restrict__ x,      // [32768, 2048]
    const float* __restrict__ w,      // [128, 2048]
    const float* __restrict__ b_ih,   // [128]
    const float* __restrict__ b_hh,   // [128]
    float* __restrict__ xp)           // [32768, 128]
{
    __shared__ __align__(16) unsigned short As[BM * LDK];
    __shared__ __align__(16) unsigned short Bs[H_DIM * LDK];

    const int tid = threadIdx.x;
    const int m0  = blockIdx.x * BM;

    // staging map: per unroll step i (0..7), rows i*16 + r0, contiguous 256B/16 lanes
    const int r0 = tid >> 4;      // 0..15
    const int c4 = tid & 15;      // float4 column within 64-float row chunk

    const int lane = tid & 63;
    const int wave = tid >> 6;
    const int wm   = (wave >> 1) * 64;
    const int wn   = (wave & 1) * 64;
    const int l16  = lane & 15;
    const int quad = lane >> 4;

    f32x4 acc[4][4] = {};

    float4 ar[8], br[8];

    auto load_tiles = [&](int k0) {
        #pragma unroll
        for (int i = 0; i < 8; ++i)
            ar[i] = *(const float4*)(x + (size_t)(m0 + i * 16 + r0) * I_DIM + k0 + c4 * 4);
        #pragma unroll
        for (int i = 0; i < 8; ++i)
            br[i] = *(const float4*)(w + (size_t)(i * 16 + r0) * I_DIM + k0 + c4 * 4);
    };

    auto store_tiles = [&]() {
        #pragma unroll
        for (int i = 0; i < 8; ++i) {
            ushort4 v;
            v.x = f2bf(ar[i].x); v.y = f2bf(ar[i].y);
            v.z = f2bf(ar[i].z); v.w = f2bf(ar[i].w);
            *(ushort4*)(As + (i * 16 + r0) * LDK + c4 * 4) = v;
        }
        #pragma unroll
        for (int i = 0; i < 8; ++i) {
            ushort4 v;
            v.x = f2bf(br[i].x); v.y = f2bf(br[i].y);
            v.z = f2bf(br[i].z); v.w = f2bf(br[i].w);
            *(ushort4*)(Bs + (i * 16 + r0) * LDK + c4 * 4) = v;
        }
    };

    load_tiles(0);

    for (int k0 = 0; k0 < I_DIM; k0 += BK) {
        __syncthreads();               // previous tile's MFMA reads done
        store_tiles();
        if (k0 + BK < I_DIM) load_tiles(k0 + BK);   // prefetch overlaps MFMA
        __syncthreads();               // staged tile visible

        #pragma unroll
        for (int kt = 0; kt < 2; ++kt) {
            bf16x8 af[4], bfr[4];
            #pragma unroll
            for (int i = 0; i < 4; ++i)
                af[i] = *(const bf16x8*)(As + (wm + i * 16 + l16) * LDK + kt * 32 + quad * 8);
            #pragma unroll
            for (int i = 0; i < 4; ++i)
                bfr[i] = *(const bf16x8*)(Bs + (wn + i * 16 + l16) * LDK + kt * 32 + quad * 8);
            #pragma unroll
            for (int i = 0; i < 4; ++i)
                #pragma unroll
                for (int j = 0; j < 4; ++j)
                    acc[i][j] = __builtin_amdgcn_mfma_f32_16x16x32_bf16(af[i], bfr[j], acc[i][j], 0, 0, 0);
        }
    }

    // epilogue: C[row][col], col = lane&15, row = quad*4 + reg   (verified m89/m91)
    #pragma unroll
    for (int j = 0; j < 4; ++j) {
        const int col  = wn + j * 16 + l16;
        const float bias = b_ih[col] + b_hh[col];
        #pragma unroll
        for (int i = 0; i < 4; ++i) {
            #pragma unroll
            for (int r = 0; r < 4; ++r) {
                const int row = wm + i * 16 + quad * 4 + r;
                xp[(size_t)(m0 + row) * H_DIM + col] = acc[i][j][r] + bias;
            }
        }
    }
}

// ---------------------------------------------------------------------------
// Kernel 2: per-batch RNN scan + FC1 + FC2 + LayerNorm. 64 blocks x 512 thr.
// Thread t: j = t>>2 (output row), q = t&3 (K-quarter). W_hh quarter-row in regs.
// h double-buffered in LDS, CHUNKED [2][4][36]: quarter q at bank offset +4q so
// the wave's 4 distinct ds_read_b128 addresses hit disjoint bank groups
// (conflict-free; 16-lane same-address reads are broadcasts).
// One raw s_barrier per step with lgkmcnt(0) only -> xp prefetch is never
// vmcnt-drained at the barrier. Quad-local reduce via shfl_xor(1)/(2) (DPP).
// ---------------------------------------------------------------------------
#define CH_PAD 36   // 32 data floats + 4 pad per chunk

__global__ __launch_bounds__(512) void rnn_tail(
    const float* __restrict__ xp,     // [64, 512, 128]  (bias pre-added)
    const float* __restrict__ Whh,    // [128, 128]
    const float* __restrict__ W1, const float* __restrict__ b1,
    const float* __restrict__ W2, const float* __restrict__ b2,
    const float* __restrict__ gamma, const float* __restrict__ beta,
    float* __restrict__ out)          // [64, 128]
{
    __shared__ float hs[2][4][CH_PAD];   // h double buffer, chunked by K-quarter
    __shared__ float zb[4][CH_PAD];      // z1, chunked
    __shared__ float red[8][2];

    const int tid = threadIdx.x;
    const int b   = blockIdx.x;
    const int j   = tid >> 2;    // output row 0..127
    const int q   = tid & 3;     // K-quarter 0..3

    // W_hh[j][q*32 .. +32) resident in 8 float4 registers
    float4 wr[8];
    {
        const float4* wrow = (const float4*)(Whh + j * H_DIM + q * 32);
        #pragma unroll
        for (int i = 0; i < 8; ++i) wr[i] = wrow[i];
    }

    if (tid < H_DIM) hs[0][tid >> 5][tid & 31] = 0.f;
    const float* xpp = xp + (size_t)b * T_STEPS * H_DIM;
    float xv = xpp[j];                 // step-0 input (same for all 4 quarters)
    __syncthreads();

    for (int t = 0; t < T_STEPS; ++t) {
        float xnext = (t < T_STEPS - 1) ? xpp[(t + 1) * H_DIM + j] : 0.f;

        const float4* hv = (const float4*)(hs[t & 1][q]);
        float p0 = 0.f, p1 = 0.f, p2 = 0.f, p3 = 0.f;
        #pragma unroll
        for (int i = 0; i < 8; i += 4) {
            float4 h0 = hv[i], h1 = hv[i + 1], h2 = hv[i + 2], h3 = hv[i + 3];
            p0 += wr[i].x     * h0.x + wr[i].y     * h0.y + wr[i].z     * h0.z + wr[i].w     * h0.w;
            p1 += wr[i + 1].x * h1.x + wr[i + 1].y * h1.y + wr[i + 1].z * h1.z + wr[i + 1].w * h1.w;
            p2 += wr[i + 2].x * h2.x + wr[i + 2].y * h2.y + wr[i + 2].z * h2.z + wr[i + 2].w * h2.w;
            p3 += wr[i + 3].x * h3.x + wr[i + 3].y * h3.y + wr[i + 3].z * h3.z + wr[i + 3].w * h3.w;
        }
        float p = (p0 + p1) + (p2 + p3);
        p += __shfl_xor(p, 1);         // quad-local: combine 4 K-quarters (DPP)
        p += __shfl_xor(p, 2);

        float a  = xv + p;
        float e  = __expf(-2.f * fabsf(a));
        float th = (1.f - e) / (1.f + e);
        th = copysignf(th, a);

        if (q == 0) hs[(t + 1) & 1][j >> 5][j & 31] = th;
        xv = xnext;
        // single barrier per step: LDS writes visible, NO vmcnt drain
        asm volatile("s_waitcnt lgkmcnt(0)" ::: "memory");
        __builtin_amdgcn_s_barrier();
        asm volatile("" ::: "memory");
    }
    // hT now in hs[0] (T_STEPS even)

    // ---- FC1: z1 = relu(hT @ W1^T + b1) ----
    {
        const float4* wv = (const float4*)(W1 + j * H_DIM + q * 32);
        const float4* hv = (const float4*)(hs[0][q]);
        float p0 = 0.f, p1 = 0.f;
        #pragma unroll
        for (int i = 0; i < 8; i += 2) {
            float4 w0 = wv[i], w1_ = wv[i + 1], h0 = hv[i], h1 = hv[i + 1];
            p0 += w0.x * h0.x + w0.y * h0.y + w0.z * h0.z + w0.w * h0.w;
            p1 += w1_.x * h1.x + w1_.y * h1.y + w1_.z * h1.z + w1_.w * h1.w;
        }
        float p = p0 + p1;
        p += __shfl_xor(p, 1);
        p += __shfl_xor(p, 2);
        float z = fmaxf(p + b1[j], 0.f);
        if (q == 0) zb[j >> 5][j & 31] = z;
    }
    __syncthreads();

    // ---- FC2: z2 = relu(z1 @ W2^T + b2) ----
    {
        const float4* wv = (const float4*)(W2 + j * H_DIM + q * 32);
        const float4* zv = (const float4*)(zb[q]);
        float p0 = 0.f, p1 = 0.f;
        #pragma unroll
        for (int i = 0; i < 8; i += 2) {
            float4 w0 = wv[i], w1_ = wv[i + 1], z0 = zv[i], z1 = zv[i + 1];
            p0 += w0.x * z0.x + w0.y * z0.y + w0.z * z0.z + w0.w * z0.w;
            p1 += w1_.x * z1.x + w1_.y * z1.y + w1_.z * z1.z + w1_.w * z1.w;
        }
        float p = p0 + p1;
        p += __shfl_xor(p, 1);
        p += __shfl_xor(p, 2);
        float z2 = fmaxf(p + b2[j], 0.f);
        if (q == 0) hs[1][j >> 5][j & 31] = z2;   // reuse hs[1] for z2
    }
    __syncthreads();

    // ---- LayerNorm over 128 features ----
    float v = (tid < H_DIM) ? hs[1][tid >> 5][tid & 31] : 0.f;
    float s = v, sq = v * v;
    #pragma unroll
    for (int o = 1; o < 64; o <<= 1) {
        s  += __shfl_xor(s, o);
        sq += __shfl_xor(sq, o);
    }
    const int lane = tid & 63, wave = tid >> 6;
    if (lane == 0) { red[wave][0] = s; red[wave][1] = sq; }
    __syncthreads();
    float S = 0.f, Q = 0.f;
    #pragma unroll
    for (int wv2 = 0; wv2 < 8; ++wv2) { S += red[wv2][0]; Q += red[wv2][1]; }
    float mu   = S * (1.f / 128.f);
    float var  = Q * (1.f / 128.f) - mu * mu;
    float rstd = rsqrtf(var + 1e-5f);
    if (tid < H_DIM)
        out[b * H_DIM + tid] = gamma[tid] * (v - mu) * rstd + beta[tid];
}

// ---------------------------------------------------------------------------
extern "C" void kernel_launch(void* const* d_in, const int* in_sizes, int n_in,
                              void* d_out, int out_size, void* d_ws, size_t ws_size,
                              hipStream_t stream) {
    const float* x     = (const float*)d_in[0];
    const float* W_ih  = (const float*)d_in[1];
    const float* b_ih  = (const float*)d_in[2];
    const float* W_hh  = (const float*)d_in[3];
    const float* b_hh  = (const float*)d_in[4];
    const float* W1    = (const float*)d_in[5];
    const float* b1    = (const float*)d_in[6];
    const float* W2    = (const float*)d_in[7];
    const float* b2    = (const float*)d_in[8];
    const float* gamma = (const float*)d_in[9];
    const float* beta  = (const float*)d_in[10];
    float* out = (float*)d_out;

    float* xp = (float*)d_ws;          // 32768*128*4 = 16 MB scratch

    gemm_xp<<<dim3(M_TOT / BM), dim3(256), 0, stream>>>(x, W_ih, b_ih, b_hh, xp);
    rnn_tail<<<dim3(B_DIM), dim3(512), 0, stream>>>(xp, W_hh, W1, b1, W2, b2,
                                                    gamma, beta, out);
}

// Round 2
// 586.052 us; speedup vs baseline: 1.1194x; 1.0498x over previous
//
#include <hip/hip_runtime.h>

// ---------------------------------------------------------------------------
// Model: xp = x @ W_ih^T + (b_ih + b_hh)   [bf16 MFMA GEMM, fp32 accumulate]
//        h_t = tanh(xp_t + h_{t-1} @ W_hh^T)   [fp32, latency-optimized scan]
//        out = LN(relu(relu(hT W1^T + b1) W2^T + b2))  [fused into RNN tail]
// ---------------------------------------------------------------------------

typedef __bf16 bf16x8 __attribute__((ext_vector_type(8)));
typedef float  f32x4  __attribute__((ext_vector_type(4)));

#define T_STEPS 512
#define I_DIM   2048
#define H_DIM   128
#define B_DIM   64
#define M_TOT   (B_DIM * T_STEPS)   // 32768

// RNE fp32 -> bf16 (inputs are finite; no NaN path needed)
__device__ __forceinline__ unsigned short f2bf(float f) {
    unsigned int u = __float_as_uint(f);
    u += 0x7FFFu + ((u >> 16) & 1u);
    return (unsigned short)(u >> 16);
}

// Quad-local sum of 4 lanes (lanes 4k..4k+3 all end with the total).
// VALU-pipe DPP quad_perm — avoids the ds_bpermute/lgkmcnt round-trips that
// __shfl_xor costs on the scan's critical path.
__device__ __forceinline__ float quad_sum(float x) {
    int t1 = __builtin_amdgcn_update_dpp(0, __float_as_int(x),
                                         0xB1 /*[1,0,3,2]*/, 0xF, 0xF, true);
    float y = x + __int_as_float(t1);
    int t2 = __builtin_amdgcn_update_dpp(0, __float_as_int(y),
                                         0x4E /*[2,3,0,1]*/, 0xF, 0xF, true);
    return y + __int_as_float(t2);
}

// ---------------------------------------------------------------------------
// Kernel 1: xp[M,128] = x[M,2048] (bf16) @ W_ih[128,2048]^T (bf16) + bias
// BM=128, BN=128(=H), BK=64. 256 threads = 4 waves in 2x2, each wave 64x64.
// fp32 -> bf16 conversion fused into LDS staging (x read exactly once).
// ---------------------------------------------------------------------------
#define BM  128
#define BK  64
#define LDK 72   // LDS row stride in bf16 elems (+8 pad -> 2-way-max bank alias)

__global__ __launch_bounds__(256) void gemm_xp(
    const float* __restrict__ x,      // [32768, 2048]
    const float* __restrict__ w,      // [128, 2048]
    const float* __restrict__ b_ih,   // [128]
    const float* __restrict__ b_hh,   // [128]
    float* __restrict__ xp)           // [32768, 128]
{
    __shared__ __align__(16) unsigned short As[BM * LDK];
    __shared__ __align__(16) unsigned short Bs[H_DIM * LDK];

    const int tid = threadIdx.x;
    const int m0  = blockIdx.x * BM;

    // staging map: per unroll step i (0..7), rows i*16 + r0, contiguous 256B/16 lanes
    const int r0 = tid >> 4;      // 0..15
    const int c4 = tid & 15;      // float4 column within 64-float row chunk

    const int lane = tid & 63;
    const int wave = tid >> 6;
    const int wm   = (wave >> 1) * 64;
    const int wn   = (wave & 1) * 64;
    const int l16  = lane & 15;
    const int quad = lane >> 4;

    f32x4 acc[4][4] = {};

    float4 ar[8], br[8];

    auto load_tiles = [&](int k0) {
        #pragma unroll
        for (int i = 0; i < 8; ++i)
            ar[i] = *(const float4*)(x + (size_t)(m0 + i * 16 + r0) * I_DIM + k0 + c4 * 4);
        #pragma unroll
        for (int i = 0; i < 8; ++i)
            br[i] = *(const float4*)(w + (size_t)(i * 16 + r0) * I_DIM + k0 + c4 * 4);
    };

    auto store_tiles = [&]() {
        #pragma unroll
        for (int i = 0; i < 8; ++i) {
            ushort4 v;
            v.x = f2bf(ar[i].x); v.y = f2bf(ar[i].y);
            v.z = f2bf(ar[i].z); v.w = f2bf(ar[i].w);
            *(ushort4*)(As + (i * 16 + r0) * LDK + c4 * 4) = v;
        }
        #pragma unroll
        for (int i = 0; i < 8; ++i) {
            ushort4 v;
            v.x = f2bf(br[i].x); v.y = f2bf(br[i].y);
            v.z = f2bf(br[i].z); v.w = f2bf(br[i].w);
            *(ushort4*)(Bs + (i * 16 + r0) * LDK + c4 * 4) = v;
        }
    };

    load_tiles(0);

    for (int k0 = 0; k0 < I_DIM; k0 += BK) {
        __syncthreads();               // previous tile's MFMA reads done
        store_tiles();
        if (k0 + BK < I_DIM) load_tiles(k0 + BK);   // prefetch overlaps MFMA
        __syncthreads();               // staged tile visible

        #pragma unroll
        for (int kt = 0; kt < 2; ++kt) {
            bf16x8 af[4], bfr[4];
            #pragma unroll
            for (int i = 0; i < 4; ++i)
                af[i] = *(const bf16x8*)(As + (wm + i * 16 + l16) * LDK + kt * 32 + quad * 8);
            #pragma unroll
            for (int i = 0; i < 4; ++i)
                bfr[i] = *(const bf16x8*)(Bs + (wn + i * 16 + l16) * LDK + kt * 32 + quad * 8);
            #pragma unroll
            for (int i = 0; i < 4; ++i)
                #pragma unroll
                for (int j = 0; j < 4; ++j)
                    acc[i][j] = __builtin_amdgcn_mfma_f32_16x16x32_bf16(af[i], bfr[j], acc[i][j], 0, 0, 0);
        }
    }

    // epilogue: C[row][col], col = lane&15, row = quad*4 + reg   (verified m89/m91)
    #pragma unroll
    for (int j = 0; j < 4; ++j) {
        const int col  = wn + j * 16 + l16;
        const float bias = b_ih[col] + b_hh[col];
        #pragma unroll
        for (int i = 0; i < 4; ++i) {
            #pragma unroll
            for (int r = 0; r < 4; ++r) {
                const int row = wm + i * 16 + quad * 4 + r;
                xp[(size_t)(m0 + row) * H_DIM + col] = acc[i][j][r] + bias;
            }
        }
    }
}

// ---------------------------------------------------------------------------
// Kernel 2: per-batch RNN scan + FC1 + FC2 + LayerNorm. 64 blocks x 512 thr.
// Thread t: j = t>>2 (output row), q = t&3 (K-quarter). W_hh quarter-row in regs.
// h double-buffered in LDS, CHUNKED [2][4][36]: quarter q at bank offset +4q so
// the wave's 4 distinct ds_read_b128 addresses hit disjoint bank groups
// (conflict-free; 16-lane same-address reads are broadcasts).
// Quad reduce via DPP quad_perm (VALU pipe) — NOT __shfl_xor (LDS pipe).
// One raw s_barrier per step with lgkmcnt(0) only -> xp prefetch is never
// vmcnt-drained at the barrier.
// ---------------------------------------------------------------------------
#define CH_PAD 36   // 32 data floats + 4 pad per chunk

__global__ __launch_bounds__(512) void rnn_tail(
    const float* __restrict__ xp,     // [64, 512, 128]  (bias pre-added)
    const float* __restrict__ Whh,    // [128, 128]
    const float* __restrict__ W1, const float* __restrict__ b1,
    const float* __restrict__ W2, const float* __restrict__ b2,
    const float* __restrict__ gamma, const float* __restrict__ beta,
    float* __restrict__ out)          // [64, 128]
{
    __shared__ float hs[2][4][CH_PAD];   // h double buffer, chunked by K-quarter
    __shared__ float zb[4][CH_PAD];      // z1, chunked
    __shared__ float red[8][2];

    const int tid = threadIdx.x;
    const int b   = blockIdx.x;
    const int j   = tid >> 2;    // output row 0..127
    const int q   = tid & 3;     // K-quarter 0..3

    // W_hh[j][q*32 .. +32) resident in 8 float4 registers
    float4 wr[8];
    {
        const float4* wrow = (const float4*)(Whh + j * H_DIM + q * 32);
        #pragma unroll
        for (int i = 0; i < 8; ++i) wr[i] = wrow[i];
    }

    if (tid < H_DIM) hs[0][tid >> 5][tid & 31] = 0.f;
    const float* xptr = xp + (size_t)b * T_STEPS * H_DIM + j;
    float xv = *xptr;                  // step-0 input (same for all 4 quarters)
    __syncthreads();

    #pragma unroll 1
    for (int t = 0; t < T_STEPS - 1; ++t) {
        float xnext = xptr[H_DIM];     // always in-bounds (t+1 <= 511)
        xptr += H_DIM;

        const float4* hv = (const float4*)(hs[t & 1][q]);
        float p0 = 0.f, p1 = 0.f, p2 = 0.f, p3 = 0.f;
        #pragma unroll
        for (int i = 0; i < 8; i += 4) {
            float4 h0 = hv[i], h1 = hv[i + 1], h2 = hv[i + 2], h3 = hv[i + 3];
            p0 += wr[i].x     * h0.x + wr[i].y     * h0.y + wr[i].z     * h0.z + wr[i].w     * h0.w;
            p1 += wr[i + 1].x * h1.x + wr[i + 1].y * h1.y + wr[i + 1].z * h1.z + wr[i + 1].w * h1.w;
            p2 += wr[i + 2].x * h2.x + wr[i + 2].y * h2.y + wr[i + 2].z * h2.z + wr[i + 2].w * h2.w;
            p3 += wr[i + 3].x * h3.x + wr[i + 3].y * h3.y + wr[i + 3].z * h3.z + wr[i + 3].w * h3.w;
        }
        float p = quad_sum((p0 + p1) + (p2 + p3));   // DPP, VALU-only

        float a  = xv + p;
        float e  = __expf(-2.f * fabsf(a));
        float th = (1.f - e) / (1.f + e);
        th = copysignf(th, a);

        if (q == 0) hs[(t + 1) & 1][j >> 5][j & 31] = th;
        xv = xnext;
        // single barrier per step: LDS writes visible, NO vmcnt drain
        asm volatile("s_waitcnt lgkmcnt(0)" ::: "memory");
        __builtin_amdgcn_s_barrier();
        asm volatile("" ::: "memory");
    }

    // final step t = T_STEPS-1 (no prefetch); writes hs[0]
    {
        const int t = T_STEPS - 1;
        const float4* hv = (const float4*)(hs[t & 1][q]);
        float p0 = 0.f, p1 = 0.f, p2 = 0.f, p3 = 0.f;
        #pragma unroll
        for (int i = 0; i < 8; i += 4) {
            float4 h0 = hv[i], h1 = hv[i + 1], h2 = hv[i + 2], h3 = hv[i + 3];
            p0 += wr[i].x     * h0.x + wr[i].y     * h0.y + wr[i].z     * h0.z + wr[i].w     * h0.w;
            p1 += wr[i + 1].x * h1.x + wr[i + 1].y * h1.y + wr[i + 1].z * h1.z + wr[i + 1].w * h1.w;
            p2 += wr[i + 2].x * h2.x + wr[i + 2].y * h2.y + wr[i + 2].z * h2.z + wr[i + 2].w * h2.w;
            p3 += wr[i + 3].x * h3.x + wr[i + 3].y * h3.y + wr[i + 3].z * h3.z + wr[i + 3].w * h3.w;
        }
        float p = quad_sum((p0 + p1) + (p2 + p3));
        float a  = xv + p;
        float e  = __expf(-2.f * fabsf(a));
        float th = (1.f - e) / (1.f + e);
        th = copysignf(th, a);
        if (q == 0) hs[0][j >> 5][j & 31] = th;
        __syncthreads();
    }
    // hT now in hs[0]

    // ---- FC1: z1 = relu(hT @ W1^T + b1) ----
    {
        const float4* wv = (const float4*)(W1 + j * H_DIM + q * 32);
        const float4* hv = (const float4*)(hs[0][q]);
        float p0 = 0.f, p1 = 0.f;
        #pragma unroll
        for (int i = 0; i < 8; i += 2) {
            float4 w0 = wv[i], w1_ = wv[i + 1], h0 = hv[i], h1 = hv[i + 1];
            p0 += w0.x * h0.x + w0.y * h0.y + w0.z * h0.z + w0.w * h0.w;
            p1 += w1_.x * h1.x + w1_.y * h1.y + w1_.z * h1.z + w1_.w * h1.w;
        }
        float p = quad_sum(p0 + p1);
        float z = fmaxf(p + b1[j], 0.f);
        if (q == 0) zb[j >> 5][j & 31] = z;
    }
    __syncthreads();

    // ---- FC2: z2 = relu(z1 @ W2^T + b2) ----
    {
        const float4* wv = (const float4*)(W2 + j * H_DIM + q * 32);
        const float4* zv = (const float4*)(zb[q]);
        float p0 = 0.f, p1 = 0.f;
        #pragma unroll
        for (int i = 0; i < 8; i += 2) {
            float4 w0 = wv[i], w1_ = wv[i + 1], z0 = zv[i], z1 = zv[i + 1];
            p0 += w0.x * z0.x + w0.y * z0.y + w0.z * z0.z + w0.w * z0.w;
            p1 += w1_.x * z1.x + w1_.y * z1.y + w1_.z * z1.z + w1_.w * z1.w;
        }
        float p = quad_sum(p0 + p1);
        float z2 = fmaxf(p + b2[j], 0.f);
        if (q == 0) hs[1][j >> 5][j & 31] = z2;   // reuse hs[1] for z2
    }
    __syncthreads();

    // ---- LayerNorm over 128 features ----
    float v = (tid < H_DIM) ? hs[1][tid >> 5][tid & 31] : 0.f;
    float s = v, sq = v * v;
    #pragma unroll
    for (int o = 1; o < 64; o <<= 1) {
        s  += __shfl_xor(s, o);
        sq += __shfl_xor(sq, o);
    }
    const int lane = tid & 63, wave = tid >> 6;
    if (lane == 0) { red[wave][0] = s; red[wave][1] = sq; }
    __syncthreads();
    float S = 0.f, Q = 0.f;
    #pragma unroll
    for (int wv2 = 0; wv2 < 8; ++wv2) { S += red[wv2][0]; Q += red[wv2][1]; }
    float mu   = S * (1.f / 128.f);
    float var  = Q * (1.f / 128.f) - mu * mu;
    float rstd = rsqrtf(var + 1e-5f);
    if (tid < H_DIM)
        out[b * H_DIM + tid] = gamma[tid] * (v - mu) * rstd + beta[tid];
}

// ---------------------------------------------------------------------------
extern "C" void kernel_launch(void* const* d_in, const int* in_sizes, int n_in,
                              void* d_out, int out_size, void* d_ws, size_t ws_size,
                              hipStream_t stream) {
    const float* x     = (const float*)d_in[0];
    const float* W_ih  = (const float*)d_in[1];
    const float* b_ih  = (const float*)d_in[2];
    const float* W_hh  = (const float*)d_in[3];
    const float* b_hh  = (const float*)d_in[4];
    const float* W1    = (const float*)d_in[5];
    const float* b1    = (const float*)d_in[6];
    const float* W2    = (const float*)d_in[7];
    const float* b2    = (const float*)d_in[8];
    const float* gamma = (const float*)d_in[9];
    const float* beta  = (const float*)d_in[10];
    float* out = (float*)d_out;

    float* xp = (float*)d_ws;          // 32768*128*4 = 16 MB scratch

    gemm_xp<<<dim3(M_TOT / BM), dim3(256), 0, stream>>>(x, W_ih, b_ih, b_hh, xp);
    rnn_tail<<<dim3(B_DIM), dim3(512), 0, stream>>>(xp, W_hh, W1, b1, W2, b2,
                                                    gamma, beta, out);
}